// Round 1
// baseline (5196.575 us; speedup 1.0000x reference)
//
#include <hip/hip_runtime.h>

#define NN 50000
#define H 150
#define H3 450
#define NE 400000
#define NG 64
#define NPASS 5

// ---------------- CSR build ----------------
__global__ void hist_kernel(const int* __restrict__ edges, int* __restrict__ cnt) {
  int id = blockIdx.x * 256 + threadIdx.x;
  if (id >= 2 * NE) return;
  int dst = edges[id * 2];           // edges flat (2,E,2): id = k*NE+e
  atomicAdd(&cnt[dst], 1);
}

__global__ void scan_kernel(const int* __restrict__ cnt, int* __restrict__ rowptr, int n) {
  __shared__ int sd[1024];
  __shared__ int carry_s;
  int t = threadIdx.x;
  if (t == 0) carry_s = 0;
  __syncthreads();
  for (int base = 0; base < n; base += 1024) {
    int idx = base + t;
    int v = (idx < n) ? cnt[idx] : 0;
    sd[t] = v;
    __syncthreads();
    for (int off = 1; off < 1024; off <<= 1) {
      int add = (t >= off) ? sd[t - off] : 0;
      __syncthreads();
      sd[t] += add;
      __syncthreads();
    }
    int c = carry_s;
    if (idx < n) rowptr[idx] = c + sd[t] - v;   // exclusive
    __syncthreads();
    if (t == 1023) carry_s = c + sd[1023];
    __syncthreads();
  }
  if (t == 0) rowptr[n] = carry_s;
}

__global__ void copy_int_kernel(const int* __restrict__ a, int* __restrict__ b, int n) {
  int id = blockIdx.x * 256 + threadIdx.x;
  if (id < n) b[id] = a[id];
}

__global__ void fill_kernel(const int* __restrict__ edges, int* __restrict__ cursor,
                            int* __restrict__ colbuf) {
  int id = blockIdx.x * 256 + threadIdx.x;
  if (id >= 2 * NE) return;
  int dst = edges[id * 2];
  int src = edges[id * 2 + 1];
  int k = id / NE;
  int pos = atomicAdd(&cursor[dst], 1);
  colbuf[pos] = k * NN + src;
}

__global__ void bounds_kernel(const int* __restrict__ gids, int* __restrict__ gstart) {
  int g = threadIdx.x;
  if (g > NG) return;
  int lo = 0, hi = NN;
  while (lo < hi) { int m = (lo + hi) >> 1; if (gids[m] < g) lo = m + 1; else hi = m; }
  gstart[g] = lo;
}

// ---------------- weight transposes (once per launch) ----------------
__global__ void transpose_kernel(const float* __restrict__ eW, const float* __restrict__ wih,
                                 const float* __restrict__ whh, float* __restrict__ eWt,
                                 float* __restrict__ wiht, float* __restrict__ whht) {
  int id = blockIdx.x * 256 + threadIdx.x;
  if (id < 2 * H * H) {
    int set = id / (H * H), rem = id % (H * H);
    int k = rem / H, c = rem % H;
    eWt[id] = eW[set * H * H + c * H + k];
  }
  if (id < H * H3) {
    int k = id / H3, o = id % H3;
    wiht[id] = wih[o * H + k];
    whht[id] = whh[o * H + k];
  }
}

// ---------------- transform: T[set*NN+r] = nodes[r] @ W_set^T + b_set ----------------
#define TKC 30
__global__ __launch_bounds__(256) void transform_kernel(
    const float* __restrict__ A, const float* __restrict__ Wt,
    const float* __restrict__ bias, float* __restrict__ T) {
  int set = blockIdx.y;
  int r0 = blockIdx.x * 64;
  const float* Wts = Wt + set * H * H;       // [k][c]
  const float* bs  = bias + set * H;
  float* Tout = T + (size_t)set * NN * H;

  __shared__ float As[TKC][64];
  __shared__ float Bs[TKC][160];

  int tid = threadIdx.x;
  int tc = tid & 31;      // col group: c = tc + 32*j
  int tr = tid >> 5;      // row group: r = tr*8 + i

  float acc[8][5];
  #pragma unroll
  for (int i = 0; i < 8; i++)
    #pragma unroll
    for (int j = 0; j < 5; j++) acc[i][j] = 0.f;

  for (int k0 = 0; k0 < H; k0 += TKC) {
    for (int e = tid; e < 64 * TKC; e += 256) {
      int r = e / TKC, k = e % TKC;
      int gr = r0 + r;
      As[k][r] = (gr < NN) ? A[(size_t)gr * H + k0 + k] : 0.f;
    }
    for (int e = tid; e < TKC * 160; e += 256) {
      int k = e / 160, c = e % 160;
      Bs[k][c] = (c < H) ? Wts[(k0 + k) * H + c] : 0.f;
    }
    __syncthreads();
    for (int k = 0; k < TKC; k++) {
      float a[8], bb[5];
      #pragma unroll
      for (int i = 0; i < 8; i++) a[i] = As[k][tr * 8 + i];
      #pragma unroll
      for (int j = 0; j < 5; j++) bb[j] = Bs[k][tc + 32 * j];
      #pragma unroll
      for (int i = 0; i < 8; i++)
        #pragma unroll
        for (int j = 0; j < 5; j++) acc[i][j] += a[i] * bb[j];
    }
    __syncthreads();
  }
  #pragma unroll
  for (int i = 0; i < 8; i++) {
    int gr = r0 + tr * 8 + i;
    if (gr >= NN) continue;
    #pragma unroll
    for (int j = 0; j < 5; j++) {
      int c = tc + 32 * j;
      if (c < H) Tout[(size_t)gr * H + c] = acc[i][j] + bs[c];
    }
  }
}

// ---------------- gather: incoming[i] = sum over CSR of T rows ----------------
__global__ __launch_bounds__(256) void gather_kernel(
    const float* __restrict__ T, const int* __restrict__ rowptr,
    const int* __restrict__ colbuf, float* __restrict__ incoming) {
  int gtid = blockIdx.x * 256 + threadIdx.x;
  int node = gtid >> 6;
  int lane = gtid & 63;
  if (node >= NN) return;
  int s = rowptr[node], e = rowptr[node + 1];
  int c0 = lane, c1 = lane + 64, c2 = lane + 128;
  bool ok2 = (c2 < H);
  float a0 = 0.f, a1 = 0.f, a2 = 0.f;
  for (int p = s; p < e; p++) {
    const float* trow = T + (size_t)colbuf[p] * H;
    a0 += trow[c0];
    a1 += trow[c1];
    if (ok2) a2 += trow[c2];
  }
  float* o = incoming + (size_t)node * H;
  o[c0] = a0; o[c1] = a1; if (ok2) o[c2] = a2;
}

// ---------------- fused GRU: gi/gh GEMMs + gate elementwise, in-place ----------------
#define GKC 30
__global__ __launch_bounds__(256) void gru_kernel(
    const float* __restrict__ incoming, float* __restrict__ nodes,
    const float* __restrict__ wiht, const float* __restrict__ whht,
    const float* __restrict__ b_ih, const float* __restrict__ b_hh) {
  int r0 = blockIdx.x * 32;
  __shared__ float As[GKC][32];
  __shared__ float Bs[3][GKC][160];
  int tid = threadIdx.x;
  int tc = tid & 31;      // c = tc + 32*j
  int tr = tid >> 5;      // r = tr*4 + i

  float sr[4][5], sz[4][5], nn[4][5], hn[4][5];
  #pragma unroll
  for (int i = 0; i < 4; i++)
    #pragma unroll
    for (int j = 0; j < 5; j++) { sr[i][j] = 0; sz[i][j] = 0; nn[i][j] = 0; hn[i][j] = 0; }

  #pragma unroll
  for (int half = 0; half < 2; half++) {
    const float* Ain = half ? (const float*)nodes : incoming;
    const float* Wt  = half ? whht : wiht;           // [k][3H]
    for (int k0 = 0; k0 < H; k0 += GKC) {
      for (int e = tid; e < 32 * GKC; e += 256) {
        int r = e / GKC, k = e % GKC;
        int gr = r0 + r;
        As[k][r] = (gr < NN) ? Ain[(size_t)gr * H + k0 + k] : 0.f;
      }
      for (int e = tid; e < 3 * GKC * 160; e += 256) {
        int p = e / (GKC * 160), rem = e % (GKC * 160);
        int k = rem / 160, c = rem % 160;
        Bs[p][k][c] = (c < H) ? Wt[(k0 + k) * H3 + p * H + c] : 0.f;
      }
      __syncthreads();
      for (int k = 0; k < GKC; k++) {
        float a[4], b0[5], b1[5], b2[5];
        #pragma unroll
        for (int i = 0; i < 4; i++) a[i] = As[k][tr * 4 + i];
        #pragma unroll
        for (int j = 0; j < 5; j++) {
          b0[j] = Bs[0][k][tc + 32 * j];
          b1[j] = Bs[1][k][tc + 32 * j];
          b2[j] = Bs[2][k][tc + 32 * j];
        }
        if (half == 0) {
          #pragma unroll
          for (int i = 0; i < 4; i++)
            #pragma unroll
            for (int j = 0; j < 5; j++) {
              sr[i][j] += a[i] * b0[j]; sz[i][j] += a[i] * b1[j]; nn[i][j] += a[i] * b2[j];
            }
        } else {
          #pragma unroll
          for (int i = 0; i < 4; i++)
            #pragma unroll
            for (int j = 0; j < 5; j++) {
              sr[i][j] += a[i] * b0[j]; sz[i][j] += a[i] * b1[j]; hn[i][j] += a[i] * b2[j];
            }
        }
      }
      __syncthreads();
    }
  }
  #pragma unroll
  for (int i = 0; i < 4; i++) {
    int gr = r0 + tr * 4 + i;
    if (gr >= NN) continue;
    #pragma unroll
    for (int j = 0; j < 5; j++) {
      int c = tc + 32 * j;
      if (c >= H) continue;
      float r_g = 1.f / (1.f + __expf(-(sr[i][j] + b_ih[c] + b_hh[c])));
      float z_g = 1.f / (1.f + __expf(-(sz[i][j] + b_ih[H + c] + b_hh[H + c])));
      float narg = nn[i][j] + b_ih[2 * H + c] + r_g * (hn[i][j] + b_hh[2 * H + c]);
      float e2 = __expf(2.f * narg);
      float n_g = 1.f - 2.f / (e2 + 1.f);         // tanh, NaN-safe at +/-inf
      float h = nodes[(size_t)gr * H + c];
      nodes[(size_t)gr * H + c] = (1.f - z_g) * n_g + z_g * h;
    }
  }
}

// ---------------- readout ----------------
__global__ __launch_bounds__(192) void segsum_kernel(const float* __restrict__ nodes,
                                                     const int* __restrict__ gstart,
                                                     float* __restrict__ gsum) {
  int g = blockIdx.x, chunk = blockIdx.y;
  int c = threadIdx.x;
  if (c >= H) return;
  int s = gstart[g], e = gstart[g + 1];
  int len = e - s;
  if (len <= 0) return;
  int per = (len + 3) / 4;
  int rs = s + chunk * per;
  int re = min(e, rs + per);
  if (rs >= re) return;
  float acc = 0.f;
  for (int r = rs; r < re; r++) acc += nodes[(size_t)r * H + c];
  atomicAdd(&gsum[g * H + c], acc);
}

__global__ __launch_bounds__(256) void head_kernel(
    const float* __restrict__ gsum, const float* __restrict__ pt,
    const float* __restrict__ fc1_w, const float* __restrict__ fc1_b,
    const float* __restrict__ fc2_w, const float* __restrict__ fc2_b,
    const float* __restrict__ fcL_w, const float* __restrict__ fcL_b,
    float* __restrict__ out) {
  __shared__ float bufA[NG * 151];   // g-features; later reused as X2
  __shared__ float X1[NG * 80];
  int tid = threadIdx.x;
  for (int e = tid; e < NG * 151; e += 256) {
    int row = e / 151, c = e % 151;
    float v;
    if (c < H) { float g = gsum[row * H + c]; v = (g > 1.f) ? logf(g) : 0.f; }
    else v = pt[row];
    bufA[e] = v;
  }
  __syncthreads();
  for (int e = tid; e < NG * 80; e += 256) {
    int row = e / 80, o = e % 80;
    float acc = fc1_b[o];
    for (int k = 0; k < 151; k++) acc += bufA[row * 151 + k] * fc1_w[o * 151 + k];
    X1[e] = (acc > 0.f) ? acc : 0.01f * acc;
  }
  __syncthreads();
  for (int e = tid; e < NG * 80; e += 256) {
    int row = e / 80, o = e % 80;
    float acc = fc2_b[o];
    for (int k = 0; k < 80; k++) acc += X1[row * 80 + k] * fc2_w[o * 80 + k];
    bufA[e] = (acc > 0.f) ? acc : 0.01f * acc;   // X2
  }
  __syncthreads();
  for (int e = tid; e < NG * 10; e += 256) {
    int row = e / 10, o = e % 10;
    float acc = fcL_b[o];
    for (int k = 0; k < 80; k++) acc += bufA[row * 80 + k] * fcL_w[o * 80 + k];
    out[e] = acc;
  }
}

extern "C" void kernel_launch(void* const* d_in, const int* in_sizes, int n_in,
                              void* d_out, int out_size, void* d_ws, size_t ws_size,
                              hipStream_t stream) {
  const float* nodes_in = (const float*)d_in[0];
  const float* problem_type = (const float*)d_in[1];
  const float* edge_W = (const float*)d_in[2];
  const float* edge_b = (const float*)d_in[3];
  const float* w_ih = (const float*)d_in[4];
  const float* w_hh = (const float*)d_in[5];
  const float* b_ih = (const float*)d_in[6];
  const float* b_hh = (const float*)d_in[7];
  const float* fc1_w = (const float*)d_in[8];
  const float* fc1_b = (const float*)d_in[9];
  const float* fc2_w = (const float*)d_in[10];
  const float* fc2_b = (const float*)d_in[11];
  const float* fcL_w = (const float*)d_in[12];
  const float* fcL_b = (const float*)d_in[13];
  const int* edges = (const int*)d_in[14];
  const int* graph_ids = (const int*)d_in[15];

  char* ws = (char*)d_ws;
  size_t off = 0;
  auto alloc = [&](size_t bytes) -> void* {
    void* p = ws + off;
    off = (off + bytes + 255) & ~(size_t)255;
    return p;
  };
  float* T        = (float*)alloc(2ull * NN * H * 4);
  float* incoming = (float*)alloc((size_t)NN * H * 4);
  float* nodes    = (float*)alloc((size_t)NN * H * 4);
  float* eWt      = (float*)alloc(2ull * H * H * 4);
  float* wiht     = (float*)alloc((size_t)H * H3 * 4);
  float* whht     = (float*)alloc((size_t)H * H3 * 4);
  int* rowptr     = (int*)alloc((NN + 1) * 4);
  int* cursor     = (int*)alloc((size_t)NN * 4);
  int* colbuf     = (int*)alloc(2ull * NE * 4);
  int* gstart     = (int*)alloc(65 * 4);
  float* gsum     = (float*)alloc((size_t)NG * H * 4);

  // ---- one-time setup (per launch) ----
  hipMemsetAsync(cursor, 0, (size_t)NN * 4, stream);          // cursor doubles as cnt
  hist_kernel<<<(2 * NE + 255) / 256, 256, 0, stream>>>(edges, cursor);
  scan_kernel<<<1, 1024, 0, stream>>>(cursor, rowptr, NN);
  copy_int_kernel<<<(NN + 255) / 256, 256, 0, stream>>>(rowptr, cursor, NN);
  fill_kernel<<<(2 * NE + 255) / 256, 256, 0, stream>>>(edges, cursor, colbuf);
  transpose_kernel<<<(H * H3 + 255) / 256, 256, 0, stream>>>(edge_W, w_ih, w_hh, eWt, wiht, whht);
  bounds_kernel<<<1, 128, 0, stream>>>(graph_ids, gstart);
  hipMemcpyAsync(nodes, nodes_in, (size_t)NN * H * 4, hipMemcpyDeviceToDevice, stream);

  // ---- 5 message-passing iterations ----
  for (int pass = 0; pass < NPASS; pass++) {
    transform_kernel<<<dim3((NN + 63) / 64, 2), 256, 0, stream>>>(nodes, eWt, edge_b, T);
    gather_kernel<<<(NN * 64 + 255) / 256, 256, 0, stream>>>(T, rowptr, colbuf, incoming);
    gru_kernel<<<(NN + 31) / 32, 256, 0, stream>>>(incoming, nodes, wiht, whht, b_ih, b_hh);
  }

  // ---- readout ----
  hipMemsetAsync(gsum, 0, (size_t)NG * H * 4, stream);
  segsum_kernel<<<dim3(NG, 4), 192, 0, stream>>>(nodes, gstart, gsum);
  head_kernel<<<1, 256, 0, stream>>>(gsum, problem_type, fc1_w, fc1_b, fc2_w, fc2_b,
                                     fcL_w, fcL_b, (float*)d_out);
}

// Round 2
// 3342.574 us; speedup vs baseline: 1.5547x; 1.5547x over previous
//
#include <hip/hip_runtime.h>

#define NN 50000
#define H 150
#define H3 450
#define NE 400000
#define NG 64
#define NPASS 5
#define KP 320          // padded K for GRU GEMM (300 real)
#define VC 640          // 4 gates x 160 padded cols

typedef __attribute__((ext_vector_type(8))) short short8;
typedef __attribute__((ext_vector_type(4))) float float4v;

// ---------------- bf16 split helpers ----------------
__device__ inline unsigned short f2bf_rn(float x) {
  union { float f; unsigned u; } v; v.f = x;
  unsigned r = v.u + 0x7fffu + ((v.u >> 16) & 1u);
  return (unsigned short)(r >> 16);
}
__device__ inline float bf2f(unsigned short h) {
  union { unsigned u; float f; } v; v.u = ((unsigned)h) << 16;
  return v.f;
}

// ---------------- CSR build ----------------
__global__ void hist_kernel(const int* __restrict__ edges, int* __restrict__ cnt) {
  int id = blockIdx.x * 256 + threadIdx.x;
  if (id >= 2 * NE) return;
  int dst = edges[id * 2];
  atomicAdd(&cnt[dst], 1);
}

__global__ void scan_kernel(const int* __restrict__ cnt, int* __restrict__ rowptr, int n) {
  __shared__ int sd[1024];
  __shared__ int carry_s;
  int t = threadIdx.x;
  if (t == 0) carry_s = 0;
  __syncthreads();
  for (int base = 0; base < n; base += 1024) {
    int idx = base + t;
    int v = (idx < n) ? cnt[idx] : 0;
    sd[t] = v;
    __syncthreads();
    for (int off = 1; off < 1024; off <<= 1) {
      int add = (t >= off) ? sd[t - off] : 0;
      __syncthreads();
      sd[t] += add;
      __syncthreads();
    }
    int c = carry_s;
    if (idx < n) rowptr[idx] = c + sd[t] - v;
    __syncthreads();
    if (t == 1023) carry_s = c + sd[1023];
    __syncthreads();
  }
  if (t == 0) rowptr[n] = carry_s;
}

__global__ void copy_int_kernel(const int* __restrict__ a, int* __restrict__ b, int n) {
  int id = blockIdx.x * 256 + threadIdx.x;
  if (id < n) b[id] = a[id];
}

__global__ void fill_kernel(const int* __restrict__ edges, int* __restrict__ cursor,
                            int* __restrict__ colbuf) {
  int id = blockIdx.x * 256 + threadIdx.x;
  if (id >= 2 * NE) return;
  int dst = edges[id * 2];
  int src = edges[id * 2 + 1];
  int k = id / NE;
  int pos = atomicAdd(&cursor[dst], 1);
  colbuf[pos] = k * NN + src;
}

__global__ void bounds_kernel(const int* __restrict__ gids, int* __restrict__ gstart) {
  int g = threadIdx.x;
  if (g > NG) return;
  int lo = 0, hi = NN;
  while (lo < hi) { int m = (lo + hi) >> 1; if (gids[m] < g) lo = m + 1; else hi = m; }
  gstart[g] = lo;
}

// ---------------- weight prep (once per launch) ----------------
__global__ void transpose_kernel(const float* __restrict__ eW, float* __restrict__ eWt) {
  int id = blockIdx.x * 256 + threadIdx.x;
  if (id < 2 * H * H) {
    int set = id / (H * H), rem = id % (H * H);
    int k = rem / H, c = rem % H;
    eWt[id] = eW[set * H * H + c * H + k];
  }
}

// Bc[vc][k] col-major-by-output (row stride KP), vc = g*160+c:
//  g0 (r):  k<150: w_ih[c][k]        ; 150<=k<300: w_hh[c][k-150]
//  g1 (z):  k<150: w_ih[150+c][k]    ; 150<=k<300: w_hh[150+c][k-150]
//  g2 (in): k<150: w_ih[300+c][k]    ; else 0
//  g3 (hn): 150<=k<300: w_hh[300+c][k-150] ; else 0
__global__ void build_B_kernel(const float* __restrict__ wih, const float* __restrict__ whh,
                               const float* __restrict__ bih, const float* __restrict__ bhh,
                               unsigned short* __restrict__ Bhi, unsigned short* __restrict__ Blo,
                               float* __restrict__ bias4) {
  int id = blockIdx.x * 256 + threadIdx.x;
  if (id < 4 * 160) {
    int g = id / 160, c = id % 160;
    float v = 0.f;
    if (c < H) {
      if (g == 0) v = bih[c] + bhh[c];
      else if (g == 1) v = bih[H + c] + bhh[H + c];
      else if (g == 2) v = bih[2 * H + c];
      else v = bhh[2 * H + c];
    }
    bias4[id] = v;
  }
  if (id >= VC * KP) return;
  int vc = id / KP, k = id % KP;
  int g = vc / 160, c = vc % 160;
  float v = 0.f;
  if (c < H && k < 2 * H) {
    if (k < H) {
      if (g == 0) v = wih[c * H + k];
      else if (g == 1) v = wih[(H + c) * H + k];
      else if (g == 2) v = wih[(2 * H + c) * H + k];
    } else {
      int kk = k - H;
      if (g == 0) v = whh[c * H + kk];
      else if (g == 1) v = whh[(H + c) * H + kk];
      else if (g == 3) v = whh[(2 * H + c) * H + kk];
    }
  }
  unsigned short h = f2bf_rn(v);
  Bhi[id] = h;
  Blo[id] = f2bf_rn(v - bf2f(h));
}

// ---------------- transform: T[set*NN+r] = nodes[r] @ W_set^T + b_set (fp32) ----------------
#define TKC 30
__global__ __launch_bounds__(256) void transform_kernel(
    const float* __restrict__ A, const float* __restrict__ Wt,
    const float* __restrict__ bias, float* __restrict__ T) {
  int set = blockIdx.y;
  int r0 = blockIdx.x * 64;
  const float* Wts = Wt + set * H * H;
  const float* bs  = bias + set * H;
  float* Tout = T + (size_t)set * NN * H;

  __shared__ float As[TKC][64];
  __shared__ float Bs[TKC][160];

  int tid = threadIdx.x;
  int tc = tid & 31;
  int tr = tid >> 5;

  float acc[8][5];
  #pragma unroll
  for (int i = 0; i < 8; i++)
    #pragma unroll
    for (int j = 0; j < 5; j++) acc[i][j] = 0.f;

  for (int k0 = 0; k0 < H; k0 += TKC) {
    for (int e = tid; e < 64 * TKC; e += 256) {
      int r = e / TKC, k = e % TKC;
      int gr = r0 + r;
      As[k][r] = (gr < NN) ? A[(size_t)gr * H + k0 + k] : 0.f;
    }
    for (int e = tid; e < TKC * 160; e += 256) {
      int k = e / 160, c = e % 160;
      Bs[k][c] = (c < H) ? Wts[(k0 + k) * H + c] : 0.f;
    }
    __syncthreads();
    for (int k = 0; k < TKC; k++) {
      float a[8], bb[5];
      #pragma unroll
      for (int i = 0; i < 8; i++) a[i] = As[k][tr * 8 + i];
      #pragma unroll
      for (int j = 0; j < 5; j++) bb[j] = Bs[k][tc + 32 * j];
      #pragma unroll
      for (int i = 0; i < 8; i++)
        #pragma unroll
        for (int j = 0; j < 5; j++) acc[i][j] += a[i] * bb[j];
    }
    __syncthreads();
  }
  #pragma unroll
  for (int i = 0; i < 8; i++) {
    int gr = r0 + tr * 8 + i;
    if (gr >= NN) continue;
    #pragma unroll
    for (int j = 0; j < 5; j++) {
      int c = tc + 32 * j;
      if (c < H) Tout[(size_t)gr * H + c] = acc[i][j] + bs[c];
    }
  }
}

// ---------------- gather ----------------
__global__ __launch_bounds__(256) void gather_kernel(
    const float* __restrict__ T, const int* __restrict__ rowptr,
    const int* __restrict__ colbuf, float* __restrict__ incoming) {
  int gtid = blockIdx.x * 256 + threadIdx.x;
  int node = gtid >> 6;
  int lane = gtid & 63;
  if (node >= NN) return;
  int s = rowptr[node], e = rowptr[node + 1];
  int c0 = lane, c1 = lane + 64, c2 = lane + 128;
  bool ok2 = (c2 < H);
  float a0 = 0.f, a1 = 0.f, a2 = 0.f;
  for (int p = s; p < e; p++) {
    const float* trow = T + (size_t)colbuf[p] * H;
    a0 += trow[c0];
    a1 += trow[c1];
    if (ok2) a2 += trow[c2];
  }
  float* o = incoming + (size_t)node * H;
  o[c0] = a0; o[c1] = a1; if (ok2) o[c2] = a2;
}

// ---------------- X = [incoming | nodes | 0] -> bf16 hi/lo (per pass) ----------------
__global__ __launch_bounds__(256) void convert_X_kernel(
    const float* __restrict__ incoming, const float* __restrict__ nodes,
    unsigned short* __restrict__ Xhi, unsigned short* __restrict__ Xlo) {
  int id = blockIdx.x * 256 + threadIdx.x;
  if (id >= NN * KP) return;
  int r = id / KP, k = id % KP;
  float v = 0.f;
  if (k < H) v = incoming[r * H + k];
  else if (k < 2 * H) v = nodes[r * H + (k - H)];
  unsigned short h = f2bf_rn(v);
  Xhi[id] = h;
  Xlo[id] = f2bf_rn(v - bf2f(h));
}

// ---------------- GRU via split-bf16 MFMA ----------------
// Block = 128 threads (2 waves), 16 rows. Wave w covers c-chunks {2t+w},
// each chunk has all 4 gate tiles -> gate combine is in-register.
// C/D layout (verified): col = lane&15, row = (lane>>4)*4 + reg.
// A frag: A[m=lane&15][k=quad*8+j]; B frag: B[n=lane&15][k=quad*8+j].
__global__ __launch_bounds__(128) void gru_mfma_kernel(
    const unsigned short* __restrict__ Xhi, const unsigned short* __restrict__ Xlo,
    const unsigned short* __restrict__ Bhi, const unsigned short* __restrict__ Blo,
    const float* __restrict__ bias4, float* __restrict__ nodes) {
  int r0 = blockIdx.x * 16;
  int wave = threadIdx.x >> 6;
  int lane = threadIdx.x & 63;
  int m = lane & 15;
  int quad = lane >> 4;

  float4v acc[5][4];
  #pragma unroll
  for (int t = 0; t < 5; t++)
    #pragma unroll
    for (int g = 0; g < 4; g++) acc[t][g] = (float4v){0.f, 0.f, 0.f, 0.f};

  const unsigned short* xh = Xhi + (size_t)(r0 + m) * KP + quad * 8;
  const unsigned short* xl = Xlo + (size_t)(r0 + m) * KP + quad * 8;

  for (int kt = 0; kt < KP / 32; kt++) {
    short8 ah = *(const short8*)(xh + kt * 32);
    short8 al = *(const short8*)(xl + kt * 32);
    #pragma unroll
    for (int t = 0; t < 5; t++) {
      int ch = 2 * t + wave;
      #pragma unroll
      for (int g = 0; g < 4; g++) {
        size_t boff = (size_t)(g * 160 + ch * 16 + m) * KP + kt * 32 + quad * 8;
        short8 bh = *(const short8*)(Bhi + boff);
        short8 bl = *(const short8*)(Blo + boff);
        float4v a = acc[t][g];
        a = __builtin_amdgcn_mfma_f32_16x16x32_bf16(ah, bh, a, 0, 0, 0);
        a = __builtin_amdgcn_mfma_f32_16x16x32_bf16(ah, bl, a, 0, 0, 0);
        a = __builtin_amdgcn_mfma_f32_16x16x32_bf16(al, bh, a, 0, 0, 0);
        acc[t][g] = a;
      }
    }
  }

  #pragma unroll
  for (int t = 0; t < 5; t++) {
    int ch = 2 * t + wave;
    int c = ch * 16 + m;
    if (c >= H) continue;
    float br  = bias4[c];
    float bz  = bias4[160 + c];
    float bin = bias4[320 + c];
    float bhn = bias4[480 + c];
    #pragma unroll
    for (int i = 0; i < 4; i++) {
      int row = r0 + quad * 4 + i;
      float r_g = 1.f / (1.f + __expf(-(acc[t][0][i] + br)));
      float z_g = 1.f / (1.f + __expf(-(acc[t][1][i] + bz)));
      float narg = acc[t][2][i] + bin + r_g * (acc[t][3][i] + bhn);
      float e2 = __expf(2.f * narg);
      float n_g = 1.f - 2.f / (e2 + 1.f);
      float h = nodes[(size_t)row * H + c];
      nodes[(size_t)row * H + c] = (1.f - z_g) * n_g + z_g * h;
    }
  }
}

// ---------------- readout ----------------
__global__ __launch_bounds__(192) void segsum_kernel(const float* __restrict__ nodes,
                                                     const int* __restrict__ gstart,
                                                     float* __restrict__ gsum) {
  int g = blockIdx.x, chunk = blockIdx.y;
  int c = threadIdx.x;
  if (c >= H) return;
  int s = gstart[g], e = gstart[g + 1];
  int len = e - s;
  if (len <= 0) return;
  int per = (len + 3) / 4;
  int rs = s + chunk * per;
  int re = min(e, rs + per);
  if (rs >= re) return;
  float acc = 0.f;
  for (int r = rs; r < re; r++) acc += nodes[(size_t)r * H + c];
  atomicAdd(&gsum[g * H + c], acc);
}

__global__ __launch_bounds__(256) void head_kernel(
    const float* __restrict__ gsum, const float* __restrict__ pt,
    const float* __restrict__ fc1_w, const float* __restrict__ fc1_b,
    const float* __restrict__ fc2_w, const float* __restrict__ fc2_b,
    const float* __restrict__ fcL_w, const float* __restrict__ fcL_b,
    float* __restrict__ out) {
  __shared__ float bufA[NG * 151];
  __shared__ float X1[NG * 80];
  int tid = threadIdx.x;
  for (int e = tid; e < NG * 151; e += 256) {
    int row = e / 151, c = e % 151;
    float v;
    if (c < H) { float g = gsum[row * H + c]; v = (g > 1.f) ? logf(g) : 0.f; }
    else v = pt[row];
    bufA[e] = v;
  }
  __syncthreads();
  for (int e = tid; e < NG * 80; e += 256) {
    int row = e / 80, o = e % 80;
    float acc = fc1_b[o];
    for (int k = 0; k < 151; k++) acc += bufA[row * 151 + k] * fc1_w[o * 151 + k];
    X1[e] = (acc > 0.f) ? acc : 0.01f * acc;
  }
  __syncthreads();
  for (int e = tid; e < NG * 80; e += 256) {
    int row = e / 80, o = e % 80;
    float acc = fc2_b[o];
    for (int k = 0; k < 80; k++) acc += X1[row * 80 + k] * fc2_w[o * 80 + k];
    bufA[e] = (acc > 0.f) ? acc : 0.01f * acc;
  }
  __syncthreads();
  for (int e = tid; e < NG * 10; e += 256) {
    int row = e / 10, o = e % 10;
    float acc = fcL_b[o];
    for (int k = 0; k < 80; k++) acc += bufA[row * 80 + k] * fcL_w[o * 80 + k];
    out[e] = acc;
  }
}

extern "C" void kernel_launch(void* const* d_in, const int* in_sizes, int n_in,
                              void* d_out, int out_size, void* d_ws, size_t ws_size,
                              hipStream_t stream) {
  const float* nodes_in = (const float*)d_in[0];
  const float* problem_type = (const float*)d_in[1];
  const float* edge_W = (const float*)d_in[2];
  const float* edge_b = (const float*)d_in[3];
  const float* w_ih = (const float*)d_in[4];
  const float* w_hh = (const float*)d_in[5];
  const float* b_ih = (const float*)d_in[6];
  const float* b_hh = (const float*)d_in[7];
  const float* fc1_w = (const float*)d_in[8];
  const float* fc1_b = (const float*)d_in[9];
  const float* fc2_w = (const float*)d_in[10];
  const float* fc2_b = (const float*)d_in[11];
  const float* fcL_w = (const float*)d_in[12];
  const float* fcL_b = (const float*)d_in[13];
  const int* edges = (const int*)d_in[14];
  const int* graph_ids = (const int*)d_in[15];

  char* ws = (char*)d_ws;
  size_t off = 0;
  auto alloc = [&](size_t bytes) -> void* {
    void* p = ws + off;
    off = (off + bytes + 255) & ~(size_t)255;
    return p;
  };
  // T (2*NN*H fp32 = 60MB) and Xhi/Xlo (2*NN*KP bf16 = 64MB) alias: T is dead
  // by the time convert_X runs (gather consumed it), rebuilt next pass.
  char* Tunion    = (char*)alloc(2ull * NN * KP * 2);   // 64MB union buffer
  float* T        = (float*)Tunion;
  unsigned short* Xhi = (unsigned short*)Tunion;
  unsigned short* Xlo = Xhi + (size_t)NN * KP;
  float* incoming = (float*)alloc((size_t)NN * H * 4);
  float* nodes    = (float*)alloc((size_t)NN * H * 4);
  float* eWt      = (float*)alloc(2ull * H * H * 4);
  unsigned short* Bhi = (unsigned short*)alloc((size_t)VC * KP * 2);
  unsigned short* Blo = (unsigned short*)alloc((size_t)VC * KP * 2);
  float* bias4    = (float*)alloc(4 * 160 * 4);
  int* rowptr     = (int*)alloc((NN + 1) * 4);
  int* cursor     = (int*)alloc((size_t)NN * 4);
  int* colbuf     = (int*)alloc(2ull * NE * 4);
  int* gstart     = (int*)alloc(65 * 4);
  float* gsum     = (float*)alloc((size_t)NG * H * 4);

  // ---- one-time setup (per launch) ----
  hipMemsetAsync(cursor, 0, (size_t)NN * 4, stream);
  hist_kernel<<<(2 * NE + 255) / 256, 256, 0, stream>>>(edges, cursor);
  scan_kernel<<<1, 1024, 0, stream>>>(cursor, rowptr, NN);
  copy_int_kernel<<<(NN + 255) / 256, 256, 0, stream>>>(rowptr, cursor, NN);
  fill_kernel<<<(2 * NE + 255) / 256, 256, 0, stream>>>(edges, cursor, colbuf);
  transpose_kernel<<<(2 * H * H + 255) / 256, 256, 0, stream>>>(edge_W, eWt);
  build_B_kernel<<<(VC * KP + 255) / 256, 256, 0, stream>>>(w_ih, w_hh, b_ih, b_hh,
                                                            Bhi, Blo, bias4);
  bounds_kernel<<<1, 128, 0, stream>>>(graph_ids, gstart);
  hipMemcpyAsync(nodes, nodes_in, (size_t)NN * H * 4, hipMemcpyDeviceToDevice, stream);

  // ---- 5 message-passing iterations ----
  for (int pass = 0; pass < NPASS; pass++) {
    transform_kernel<<<dim3((NN + 63) / 64, 2), 256, 0, stream>>>(nodes, eWt, edge_b, T);
    gather_kernel<<<(NN * 64 + 255) / 256, 256, 0, stream>>>(T, rowptr, colbuf, incoming);
    convert_X_kernel<<<(NN * KP + 255) / 256, 256, 0, stream>>>(incoming, nodes, Xhi, Xlo);
    gru_mfma_kernel<<<NN / 16, 128, 0, stream>>>(Xhi, Xlo, Bhi, Blo, bias4, nodes);
  }

  // ---- readout ----
  hipMemsetAsync(gsum, 0, (size_t)NG * H * 4, stream);
  segsum_kernel<<<dim3(NG, 4), 192, 0, stream>>>(nodes, gstart, gsum);
  head_kernel<<<1, 256, 0, stream>>>(gsum, problem_type, fc1_w, fc1_b, fc2_w, fc2_b,
                                     fcL_w, fcL_b, (float*)d_out);
}

// Round 3
// 1756.282 us; speedup vs baseline: 2.9588x; 1.9032x over previous
//
#include <hip/hip_runtime.h>
#include <stdint.h>

#define NN 50000
#define NS 152          // padded fp32 node row stride (608 B, 16B-aligned rows)
#define H 150
#define NE 400000
#define NG 64
#define NPASS 5
#define KB 480          // GRU GEMM K: [S0(160) | S1(160) | nodes(160)]
#define VC 640          // 40 col-tiles: v = cc*64 + g*16 + cl, c = cc*16+cl

typedef unsigned short u16;
typedef __attribute__((ext_vector_type(8))) short short8;
typedef __attribute__((ext_vector_type(4))) float float4v;

// ---------------- helpers ----------------
__device__ __forceinline__ u16 f2bf_rn(float x) {
  union { float f; unsigned u; } v; v.f = x;
  unsigned r = v.u + 0x7fffu + ((v.u >> 16) & 1u);
  return (u16)(r >> 16);
}
__device__ __forceinline__ float bf2f(u16 h) {
  union { unsigned u; float f; } v; v.u = ((unsigned)h) << 16;
  return v.f;
}
// async global->LDS, 16B per lane; lds dest must be wave-uniform base
__device__ __forceinline__ void async16(const void* g, void* l) {
  __builtin_amdgcn_global_load_lds(
      (const __attribute__((address_space(1))) unsigned int*)(uintptr_t)g,
      (__attribute__((address_space(3))) unsigned int*)(uint32_t)(uintptr_t)l,
      16, 0, 0);
}

// ---------------- CSR build (key = node*2 + set) ----------------
__global__ void hist_kernel(const int* __restrict__ edges, int* __restrict__ cnt) {
  int id = blockIdx.x * 256 + threadIdx.x;
  if (id >= 2 * NE) return;
  int dst = edges[id * 2];
  int set = id / NE;
  atomicAdd(&cnt[dst * 2 + set], 1);
}

__global__ void scan_kernel(const int* __restrict__ cnt, int* __restrict__ rowptr, int n) {
  __shared__ int sd[1024];
  __shared__ int carry_s;
  int t = threadIdx.x;
  if (t == 0) carry_s = 0;
  __syncthreads();
  for (int base = 0; base < n; base += 1024) {
    int idx = base + t;
    int v = (idx < n) ? cnt[idx] : 0;
    sd[t] = v;
    __syncthreads();
    for (int off = 1; off < 1024; off <<= 1) {
      int add = (t >= off) ? sd[t - off] : 0;
      __syncthreads();
      sd[t] += add;
      __syncthreads();
    }
    int c = carry_s;
    if (idx < n) rowptr[idx] = c + sd[t] - v;   // exclusive
    __syncthreads();
    if (t == 1023) carry_s = c + sd[1023];
    __syncthreads();
  }
  if (t == 0) rowptr[n] = carry_s;
}

__global__ void copy_int_kernel(const int* __restrict__ a, int* __restrict__ b, int n) {
  int id = blockIdx.x * 256 + threadIdx.x;
  if (id < n) b[id] = a[id];
}

__global__ void fill_kernel(const int* __restrict__ edges, int* __restrict__ cursor,
                            u16* __restrict__ colbuf) {
  int id = blockIdx.x * 256 + threadIdx.x;
  if (id >= 2 * NE) return;
  int dst = edges[id * 2];
  int src = edges[id * 2 + 1];
  int set = id / NE;
  int pos = atomicAdd(&cursor[dst * 2 + set], 1);
  colbuf[pos] = (u16)src;
}

__global__ void bounds_kernel(const int* __restrict__ gids, int* __restrict__ gstart) {
  int g = threadIdx.x;
  if (g > NG) return;
  int lo = 0, hi = NN;
  while (lo < hi) { int m = (lo + hi) >> 1; if (gids[m] < g) lo = m + 1; else hi = m; }
  gstart[g] = lo;
}

// ---------------- one-time weight prep ----------------
// B'[v][k], v in [0,640): g=(v>>4)&3, c=(v>>6)*16+(v&15)
// k<160: (W_ihg @ W0)[c][k]      (g<3; g3=0)
// 160<=k<320: (W_ihg @ W1)[c][k-160]
// 320<=k<480: g0: w_hh[c][kk], g1: w_hh[150+c][kk], g3: w_hh[300+c][kk], g2: 0
__global__ void build_B_kernel(const float* __restrict__ wih, const float* __restrict__ whh,
                               const float* __restrict__ eW,
                               u16* __restrict__ Bh, u16* __restrict__ Bl) {
  int id = blockIdx.x * 256 + threadIdx.x;
  if (id >= VC * KB) return;
  int v = id / KB, k = id % KB;
  int g = (v >> 4) & 3, c = (v >> 6) * 16 + (v & 15);
  int seg = k / 160, kk = k % 160;
  float val = 0.f;
  if (c < H && kk < H) {
    if (seg < 2) {
      if (g < 3) {
        const float* wr = wih + (size_t)(g * H + c) * H;
        const float* wc = eW + (size_t)seg * H * H + kk;
        float acc = 0.f;
        for (int t = 0; t < H; t++) acc += wr[t] * wc[(size_t)t * H];
        val = acc;
      }
    } else {
      if (g == 0) val = whh[(size_t)c * H + kk];
      else if (g == 1) val = whh[(size_t)(H + c) * H + kk];
      else if (g == 3) val = whh[(size_t)(2 * H + c) * H + kk];
    }
  }
  u16 h = f2bf_rn(val);
  Bh[id] = h;
  Bl[id] = f2bf_rn(val - bf2f(h));
}

// coefs[0][g*160+c] = W_ihg @ b0 (deg0 coef), coefs[1] = W_ihg @ b1, coefs[2] = gate bias
__global__ void build_coef_kernel(const float* __restrict__ wih,
                                  const float* __restrict__ eb,
                                  const float* __restrict__ bih, const float* __restrict__ bhh,
                                  float* __restrict__ coefs) {
  int id = threadIdx.x + blockIdx.x * 256;
  if (id >= VC) return;
  int g = id / 160, c = id % 160;
  float u0 = 0.f, u1 = 0.f, bs = 0.f;
  if (c < H) {
    if (g < 3) {
      const float* wr = wih + (size_t)(g * H + c) * H;
      for (int t = 0; t < H; t++) { u0 += wr[t] * eb[t]; u1 += wr[t] * eb[H + t]; }
    }
    if (g == 0) bs = bih[c] + bhh[c];
    else if (g == 1) bs = bih[H + c] + bhh[H + c];
    else if (g == 2) bs = bih[2 * H + c];
    else bs = bhh[2 * H + c];
  }
  coefs[id] = u0;
  coefs[VC + id] = u1;
  coefs[2 * VC + id] = bs;
}

__global__ void init_nodes_kernel(const float* __restrict__ nin, float* __restrict__ nodes) {
  int id = blockIdx.x * 256 + threadIdx.x;
  if (id >= NN * NS) return;
  int r = id / NS, c = id % NS;
  nodes[id] = (c < H) ? nin[(size_t)r * H + c] : 0.f;
}

__global__ void pad_S_kernel(u16* __restrict__ Sh, u16* __restrict__ Sl) {
  int id = blockIdx.x * 256 + threadIdx.x;
  if (id >= NN * 20) return;
  int r = id / 20, rem = id % 20;
  int set = rem / 10, t = rem % 10;
  size_t off = (size_t)r * 320 + set * 160 + H + t;
  Sh[off] = 0; Sl[off] = 0;
}

// ---------------- gather: S[n][set*160+c] = sum of raw node rows ----------------
__global__ __launch_bounds__(256) void gather_kernel(
    const float* __restrict__ nodes, const int* __restrict__ rowptr,
    const u16* __restrict__ colbuf, u16* __restrict__ Sh, u16* __restrict__ Sl) {
  int gtid = blockIdx.x * 256 + threadIdx.x;
  int node = gtid >> 6;
  int lane = gtid & 63;
  if (node >= NN) return;
  int s = rowptr[2 * node], mid = rowptr[2 * node + 1], e = rowptr[2 * node + 2];
  int c0 = lane, c1 = lane + 64, c2 = lane + 128;
  bool ok2 = (c2 < H);
  float a0 = 0.f, a1 = 0.f, a2 = 0.f;
  for (int p = s; p < mid; p++) {
    const float* row = nodes + (size_t)colbuf[p] * NS;
    a0 += row[c0]; a1 += row[c1]; if (ok2) a2 += row[c2];
  }
  float b0 = 0.f, b1 = 0.f, b2 = 0.f;
  for (int p = mid; p < e; p++) {
    const float* row = nodes + (size_t)colbuf[p] * NS;
    b0 += row[c0]; b1 += row[c1]; if (ok2) b2 += row[c2];
  }
  u16* oh = Sh + (size_t)node * 320;
  u16* ol = Sl + (size_t)node * 320;
  u16 h;
  h = f2bf_rn(a0); oh[c0] = h; ol[c0] = f2bf_rn(a0 - bf2f(h));
  h = f2bf_rn(a1); oh[c1] = h; ol[c1] = f2bf_rn(a1 - bf2f(h));
  if (ok2) { h = f2bf_rn(a2); oh[c2] = h; ol[c2] = f2bf_rn(a2 - bf2f(h)); }
  h = f2bf_rn(b0); oh[160 + c0] = h; ol[160 + c0] = f2bf_rn(b0 - bf2f(h));
  h = f2bf_rn(b1); oh[160 + c1] = h; ol[160 + c1] = f2bf_rn(b1 - bf2f(h));
  if (ok2) { h = f2bf_rn(b2); oh[160 + c2] = h; ol[160 + c2] = f2bf_rn(b2 - bf2f(h)); }
}

// ---------------- fused GRU GEMM: C[NN x 640] = X[NN x 480] @ B'^T, epilogue gates ----
// 128x128 tile, 256 thr / 4 waves; wave w: rows [w*32, w*32+32) (2 m-tiles), all 8 n-tiles.
// LDS XOR-swizzle; split-bf16 3-product; nodes half staged fp32, split in-register.
__global__ __launch_bounds__(256) void gru_gemm_kernel(
    const u16* __restrict__ Sh, const u16* __restrict__ Sl,
    const float* __restrict__ ncur,
    const u16* __restrict__ Bh, const u16* __restrict__ Bl,
    const float* __restrict__ coefs, const int* __restrict__ rowptr,
    float* __restrict__ nnxt) {
  __shared__ char Abuf[16384];   // S-kts: [0,8K)=hi, [8K,16K)=lo ; node-kts: fp32 tile
  __shared__ char Bbuf[16384];   // [0,8K)=hi, [8K,16K)=lo
  const int r0 = blockIdx.x * 128;
  const int ccb = blockIdx.y;          // n-tile block: vcols [ccb*128, +128)
  const int tid = threadIdx.x;
  const int w = tid >> 6, l = tid & 63;
  const int m = l & 15, quad = l >> 4;

  float4v acc[2][8];
  #pragma unroll
  for (int mt = 0; mt < 2; mt++)
    #pragma unroll
    for (int j = 0; j < 8; j++) acc[mt][j] = (float4v){0.f, 0.f, 0.f, 0.f};

  // ---- K phase 1: S half (bf16 hi/lo), kt 0..9 ----
  #pragma unroll 1
  for (int kt = 0; kt < 10; kt++) {
    int koff = kt * 32;
    #pragma unroll
    for (int i = 0; i < 2; i++) {
      int cl = (w * 2 + i) * 64 + l;              // [0,512)
      int row = cl >> 2;
      int q = (cl & 3) ^ ((row >> 1) & 3);
      int rg = min(r0 + row, NN - 1);
      size_t go = (size_t)rg * 320 + koff + q * 8;
      async16(Sh + go, Abuf + (w * 2 + i) * 1024);
      async16(Sl + go, Abuf + 8192 + (w * 2 + i) * 1024);
      int vrow = ccb * 128 + row;
      size_t gb = (size_t)vrow * KB + koff + q * 8;
      async16(Bh + gb, Bbuf + (w * 2 + i) * 1024);
      async16(Bl + gb, Bbuf + 8192 + (w * 2 + i) * 1024);
    }
    __syncthreads();
    short8 ah[2], al[2];
    #pragma unroll
    for (int mt = 0; mt < 2; mt++) {
      int r = w * 32 + mt * 16 + m;
      int ad = r * 64 + ((quad ^ ((r >> 1) & 3)) * 16);
      ah[mt] = *(const short8*)(Abuf + ad);
      al[mt] = *(const short8*)(Abuf + 8192 + ad);
    }
    #pragma unroll
    for (int j = 0; j < 8; j++) {
      int br = j * 16 + m;
      int bd = br * 64 + ((quad ^ ((br >> 1) & 3)) * 16);
      short8 bh = *(const short8*)(Bbuf + bd);
      short8 bl = *(const short8*)(Bbuf + 8192 + bd);
      #pragma unroll
      for (int mt = 0; mt < 2; mt++) {
        acc[mt][j] = __builtin_amdgcn_mfma_f32_16x16x32_bf16(ah[mt], bh, acc[mt][j], 0, 0, 0);
        acc[mt][j] = __builtin_amdgcn_mfma_f32_16x16x32_bf16(ah[mt], bl, acc[mt][j], 0, 0, 0);
        acc[mt][j] = __builtin_amdgcn_mfma_f32_16x16x32_bf16(al[mt], bh, acc[mt][j], 0, 0, 0);
      }
    }
    __syncthreads();
  }

  // ---- K phase 2: nodes half (fp32 staged, split in-register), kt 10..14 ----
  #pragma unroll 1
  for (int kt = 0; kt < 5; kt++) {
    int koff = kt * 32;
    #pragma unroll
    for (int i = 0; i < 4; i++) {
      int cl = (w * 4 + i) * 64 + l;              // [0,1024)
      int row = cl >> 3;
      int q = (cl & 7) ^ (row & 7);
      int rg = min(r0 + row, NN - 1);
      async16(ncur + (size_t)rg * NS + koff + q * 4, Abuf + (w * 4 + i) * 1024);
    }
    #pragma unroll
    for (int i = 0; i < 2; i++) {
      int cl = (w * 2 + i) * 64 + l;
      int row = cl >> 2;
      int q = (cl & 3) ^ ((row >> 1) & 3);
      int vrow = ccb * 128 + row;
      size_t gb = (size_t)vrow * KB + 320 + koff + q * 8;
      async16(Bh + gb, Bbuf + (w * 2 + i) * 1024);
      async16(Bl + gb, Bbuf + 8192 + (w * 2 + i) * 1024);
    }
    __syncthreads();
    short8 ah[2], al[2];
    #pragma unroll
    for (int mt = 0; mt < 2; mt++) {
      int r = w * 32 + mt * 16 + m;
      float4v f0 = *(const float4v*)(Abuf + r * 128 + (((2 * quad) ^ (r & 7)) * 16));
      float4v f1 = *(const float4v*)(Abuf + r * 128 + (((2 * quad + 1) ^ (r & 7)) * 16));
      float fv[8] = {f0.x, f0.y, f0.z, f0.w, f1.x, f1.y, f1.z, f1.w};
      #pragma unroll
      for (int e2 = 0; e2 < 8; e2++) {
        union { float f; unsigned u; } uv; uv.f = fv[e2];
        u16 hh = (u16)(uv.u >> 16);               // truncation split
        ah[mt][e2] = (short)hh;
        al[mt][e2] = (short)f2bf_rn(fv[e2] - bf2f(hh));
      }
    }
    #pragma unroll
    for (int j = 0; j < 8; j++) {
      int br = j * 16 + m;
      int bd = br * 64 + ((quad ^ ((br >> 1) & 3)) * 16);
      short8 bh = *(const short8*)(Bbuf + bd);
      short8 bl = *(const short8*)(Bbuf + 8192 + bd);
      #pragma unroll
      for (int mt = 0; mt < 2; mt++) {
        acc[mt][j] = __builtin_amdgcn_mfma_f32_16x16x32_bf16(ah[mt], bh, acc[mt][j], 0, 0, 0);
        acc[mt][j] = __builtin_amdgcn_mfma_f32_16x16x32_bf16(ah[mt], bl, acc[mt][j], 0, 0, 0);
        acc[mt][j] = __builtin_amdgcn_mfma_f32_16x16x32_bf16(al[mt], bh, acc[mt][j], 0, 0, 0);
      }
    }
    __syncthreads();
  }

  // ---- epilogue: gate math; tiles j = jg*4 + g (gates of c-chunk cc=2*ccb+jg) ----
  #pragma unroll
  for (int mt = 0; mt < 2; mt++) {
    #pragma unroll
    for (int jg = 0; jg < 2; jg++) {
      int c = (2 * ccb + jg) * 16 + m;
      if (c >= H) continue;
      float u0r = coefs[c],            u0z = coefs[160 + c],
            u0n = coefs[320 + c];
      float u1r = coefs[VC + c],       u1z = coefs[VC + 160 + c],
            u1n = coefs[VC + 320 + c];
      float bsr = coefs[2 * VC + c],   bsz = coefs[2 * VC + 160 + c],
            bsn = coefs[2 * VC + 320 + c], bsh = coefs[2 * VC + 480 + c];
      #pragma unroll
      for (int i = 0; i < 4; i++) {
        int row = r0 + w * 32 + mt * 16 + quad * 4 + i;
        if (row >= NN) continue;
        float d0 = (float)(rowptr[2 * row + 1] - rowptr[2 * row]);
        float d1 = (float)(rowptr[2 * row + 2] - rowptr[2 * row + 1]);
        float pr = acc[mt][jg * 4 + 0][i] + d0 * u0r + d1 * u1r + bsr;
        float pz = acc[mt][jg * 4 + 1][i] + d0 * u0z + d1 * u1z + bsz;
        float pn = acc[mt][jg * 4 + 2][i] + d0 * u0n + d1 * u1n + bsn;
        float ph = acc[mt][jg * 4 + 3][i] + bsh;
        float r_g = 1.f / (1.f + __expf(-pr));
        float z_g = 1.f / (1.f + __expf(-pz));
        float narg = pn + r_g * ph;
        float e2 = __expf(2.f * narg);
        float n_g = 1.f - 2.f / (e2 + 1.f);       // tanh, inf-safe
        float h = ncur[(size_t)row * NS + c];
        nnxt[(size_t)row * NS + c] = (1.f - z_g) * n_g + z_g * h;
      }
    }
  }
}

// ---------------- readout ----------------
__global__ __launch_bounds__(192) void segsum_kernel(const float* __restrict__ nodes,
                                                     const int* __restrict__ gstart,
                                                     float* __restrict__ gsum) {
  int g = blockIdx.x, chunk = blockIdx.y;
  int c = threadIdx.x;
  if (c >= H) return;
  int s = gstart[g], e = gstart[g + 1];
  int len = e - s;
  if (len <= 0) return;
  int per = (len + 3) / 4;
  int rs = s + chunk * per;
  int re = min(e, rs + per);
  if (rs >= re) return;
  float acc = 0.f;
  for (int r = rs; r < re; r++) acc += nodes[(size_t)r * NS + c];
  atomicAdd(&gsum[g * H + c], acc);
}

__global__ __launch_bounds__(256) void head_kernel(
    const float* __restrict__ gsum, const float* __restrict__ pt,
    const float* __restrict__ fc1_w, const float* __restrict__ fc1_b,
    const float* __restrict__ fc2_w, const float* __restrict__ fc2_b,
    const float* __restrict__ fcL_w, const float* __restrict__ fcL_b,
    float* __restrict__ out) {
  __shared__ float bufA[NG * 151];
  __shared__ float X1[NG * 80];
  int tid = threadIdx.x;
  for (int e = tid; e < NG * 151; e += 256) {
    int row = e / 151, c = e % 151;
    float v;
    if (c < H) { float g = gsum[row * H + c]; v = (g > 1.f) ? logf(g) : 0.f; }
    else v = pt[row];
    bufA[e] = v;
  }
  __syncthreads();
  for (int e = tid; e < NG * 80; e += 256) {
    int row = e / 80, o = e % 80;
    float acc = fc1_b[o];
    for (int k = 0; k < 151; k++) acc += bufA[row * 151 + k] * fc1_w[o * 151 + k];
    X1[e] = (acc > 0.f) ? acc : 0.01f * acc;
  }
  __syncthreads();
  for (int e = tid; e < NG * 80; e += 256) {
    int row = e / 80, o = e % 80;
    float acc = fc2_b[o];
    for (int k = 0; k < 80; k++) acc += X1[row * 80 + k] * fc2_w[o * 80 + k];
    bufA[e] = (acc > 0.f) ? acc : 0.01f * acc;
  }
  __syncthreads();
  for (int e = tid; e < NG * 10; e += 256) {
    int row = e / 10, o = e % 10;
    float acc = fcL_b[o];
    for (int k = 0; k < 80; k++) acc += bufA[row * 80 + k] * fcL_w[o * 80 + k];
    out[e] = acc;
  }
}

extern "C" void kernel_launch(void* const* d_in, const int* in_sizes, int n_in,
                              void* d_out, int out_size, void* d_ws, size_t ws_size,
                              hipStream_t stream) {
  const float* nodes_in = (const float*)d_in[0];
  const float* problem_type = (const float*)d_in[1];
  const float* edge_W = (const float*)d_in[2];
  const float* edge_b = (const float*)d_in[3];
  const float* w_ih = (const float*)d_in[4];
  const float* w_hh = (const float*)d_in[5];
  const float* b_ih = (const float*)d_in[6];
  const float* b_hh = (const float*)d_in[7];
  const float* fc1_w = (const float*)d_in[8];
  const float* fc1_b = (const float*)d_in[9];
  const float* fc2_w = (const float*)d_in[10];
  const float* fc2_b = (const float*)d_in[11];
  const float* fcL_w = (const float*)d_in[12];
  const float* fcL_b = (const float*)d_in[13];
  const int* edges = (const int*)d_in[14];
  const int* graph_ids = (const int*)d_in[15];

  char* ws = (char*)d_ws;
  size_t off = 0;
  auto alloc = [&](size_t bytes) -> void* {
    void* p = ws + off;
    off = (off + bytes + 255) & ~(size_t)255;
    return p;
  };
  // ws budget <= ~128.5 MB (proven available in prior rounds)
  float* nodesA = (float*)alloc((size_t)NN * NS * 4);          // 30.4 MB
  float* nodesB = (float*)alloc((size_t)NN * NS * 4);          // 30.4 MB
  u16* Sh       = (u16*)alloc((size_t)NN * 320 * 2);           // 32 MB
  u16* Sl       = (u16*)alloc((size_t)NN * 320 * 2);           // 32 MB
  u16* Bh       = (u16*)alloc((size_t)VC * KB * 2);            // 0.61 MB
  u16* Bl       = (u16*)alloc((size_t)VC * KB * 2);            // 0.61 MB
  float* coefs  = (float*)alloc(3 * VC * 4);
  int* rowptr   = (int*)alloc((2 * NN + 1) * 4);
  int* cursor   = (int*)alloc(2 * NN * 4);
  u16* colbuf   = (u16*)alloc(2ull * NE * 2);                  // 1.6 MB
  int* gstart   = (int*)alloc((NG + 1) * 4);
  float* gsum   = (float*)alloc((size_t)NG * H * 4);

  // ---- one-time setup ----
  hipMemsetAsync(cursor, 0, 2 * NN * 4, stream);
  hist_kernel<<<(2 * NE + 255) / 256, 256, 0, stream>>>(edges, cursor);
  scan_kernel<<<1, 1024, 0, stream>>>(cursor, rowptr, 2 * NN);
  copy_int_kernel<<<(2 * NN + 255) / 256, 256, 0, stream>>>(rowptr, cursor, 2 * NN);
  fill_kernel<<<(2 * NE + 255) / 256, 256, 0, stream>>>(edges, cursor, colbuf);
  bounds_kernel<<<1, 128, 0, stream>>>(graph_ids, gstart);
  build_B_kernel<<<(VC * KB + 255) / 256, 256, 0, stream>>>(w_ih, w_hh, edge_W, Bh, Bl);
  build_coef_kernel<<<(VC + 255) / 256, 256, 0, stream>>>(w_ih, edge_b, b_ih, b_hh, coefs);
  init_nodes_kernel<<<(NN * NS + 255) / 256, 256, 0, stream>>>(nodes_in, nodesA);
  pad_S_kernel<<<(NN * 20 + 255) / 256, 256, 0, stream>>>(Sh, Sl);

  // ---- 5 message-passing iterations (nodes ping-pong) ----
  float* nbuf[2] = {nodesA, nodesB};
  for (int pass = 0; pass < NPASS; pass++) {
    float* cur = nbuf[pass & 1];
    float* nxt = nbuf[1 - (pass & 1)];
    gather_kernel<<<(NN * 64 + 255) / 256, 256, 0, stream>>>(cur, rowptr, colbuf, Sh, Sl);
    gru_gemm_kernel<<<dim3((NN + 127) / 128, VC / 128), 256, 0, stream>>>(
        Sh, Sl, cur, Bh, Bl, coefs, rowptr, nxt);
  }
  float* fin = nbuf[NPASS & 1];

  // ---- readout ----
  hipMemsetAsync(gsum, 0, (size_t)NG * H * 4, stream);
  segsum_kernel<<<dim3(NG, 4), 192, 0, stream>>>(fin, gstart, gsum);
  head_kernel<<<1, 256, 0, stream>>>(gsum, problem_type, fc1_w, fc1_b, fc2_w, fc2_b,
                                     fcL_w, fcL_b, (float*)d_out);
}